// Round 5
// baseline (231.321 us; speedup 1.0000x reference)
//
#include <hip/hip_runtime.h>

// QuantumRecurrentUnit, exact Heisenberg closed form.
//   rev_q = (p_q + x_q)/2pi ;  sa=sin, ca=cos of the angle
//   p_q' = cos(th_q)*prefixprod_{j<=q} ca_j - sin(th_q)*(q<5 ? sa_q*sa_{q+1} : sa_5)
//
// v6: LONG WINDOWS — attack total work, not scheduling.
// Five rounds measured an invariant ~5.4-7.2 cy/lane-step across completely
// different designs (LDS-staged, all-global, 68 or 32 VGPRs, 8-18 waves/CU).
// The only untouched lever is lane-step COUNT: S=8 paid a 5x burn-in tax
// (40 steps / 8 outputs). S=64 with the same verified W=32 burn-in pays 1.5x:
// total lane-steps 10.5M -> 3.1M (3.4x less trans/VALU/memory work).
//   - 32768 windows (2048 chains x 16), one lane each; 512 one-wave blocks
//     -> 2 waves/CU, grid-limited occupancy (~6%) by design.
//   - zero LDS, zero syncthreads. Loads are per-lane scatter (each row read
//     by exactly one lane; ~1.5x compulsory fetch) -- v4 measured this
//     pattern at 5.4 cy/lane-step, so scatter is affordable at 3.4x less work.
//   - group-of-6 register prefetch: loads for row-group g+1 issued before
//     computing group g, fenced with sched_barrier(0) (v1's proven staging
//     idiom) so ~600 cy of trans/VALU covers load latency. 2x36 buffer regs.
//   - only window k=0 crosses t=0 (tbase=-32): burn-in clamps to row 0, then
//     exact p=0 reset fires at i==W -- its outputs are exact, identical
//     mechanism to v1. Other windows: same W=32 contraction as verified.
//   - launch_bounds(64,2): 256-VGPR budget; occupancy is grid-limited anyway,
//     so give the allocator room (v3/v4's 32-VGPR crush must not recur).
//   - paired float4 stores (v5 scheme): pair base row = 64k+even ->
//     byte offset 1536k+48m, 16B-aligned.

constexpr int T = 1024;
constexpr int NQ = 6;
constexpr int S = 64;        // output steps per window
constexpr int W = 32;        // burn-in steps (accuracy knob -- unchanged)
constexpr int TOT = W + S;   // 96
constexpr int G = 6;         // rows per prefetch group
constexpr int NG = TOT / G;  // 16
constexpr int WPC = T / S;   // 16 windows per chain
constexpr float INV2PI = 0.15915494309189535f;  // v_sin/v_cos take revolutions

__global__ __launch_bounds__(64, 2) void qru_kernel(const float* __restrict__ x,
                                                    const float* __restrict__ w,
                                                    float* __restrict__ out) {
  const int lane = threadIdx.x;                  // 0..63
  const int gw = blockIdx.x * 64 + lane;         // global window id
  const int chain = gw >> 4;                     // gw / WPC
  const int k = gw & (WPC - 1);                  // window index in chain
  const float* __restrict__ xb = x + (size_t)chain * (T * 16);
  float* __restrict__ ob = out + (size_t)chain * (T * NQ);
  const int tbase = k * S - W;                   // k=0: -32 (crosses t=0)

  float cth[NQ], sth[NQ];
#pragma unroll
  for (int q = 0; q < NQ; ++q) {
    const float th = w[q];
    cth[q] = cosf(th);
    sth[q] = sinf(th);
  }

  float p[NQ];
#pragma unroll
  for (int q = 0; q < NQ; ++q) p[q] = 0.0f;

  float bufA[G][NQ], bufB[G][NQ];  // prescaled angle row-groups
  float sv[NQ];                    // buffered even output row

  // Load rows [GI*G, GI*G+G) of this window into BUF, prescaled by 1/2pi.
  // Row r and its float4/float2 halves live in one 64-B line (x rows are
  // 64 B, 64-B aligned).
#define LOADG(GI, BUF)                                                         \
  do {                                                                         \
    _Pragma("unroll") for (int r_ = 0; r_ < G; ++r_) {                         \
      int row_ = tbase + (GI) * G + r_;                                        \
      row_ = row_ < 0 ? 0 : row_; /* k=0 burn-in underrun: dummy row 0 */      \
      const float* rp_ = xb + (size_t)row_ * 16;                               \
      const float4 v4_ = *(const float4*)rp_;                                  \
      const float2 v2_ = *(const float2*)(rp_ + 4);                            \
      BUF[r_][0] = v4_.x * INV2PI;                                             \
      BUF[r_][1] = v4_.y * INV2PI;                                             \
      BUF[r_][2] = v4_.z * INV2PI;                                             \
      BUF[r_][3] = v4_.w * INV2PI;                                             \
      BUF[r_][4] = v2_.x * INV2PI;                                             \
      BUF[r_][5] = v2_.y * INV2PI;                                             \
    }                                                                          \
  } while (0)

  // Compute the G steps of group GI from BUF (all indices compile-time).
#define STEPS(GI, BUF)                                                         \
  do {                                                                         \
    _Pragma("unroll") for (int j_ = 0; j_ < G; ++j_) {                         \
      const int i_ = (GI) * G + j_;                                            \
      if (i_ == W) { /* window k=0 reaches t=0 exactly here: exact restart */  \
        const bool rs_ = (tbase + W == 0);                                     \
        _Pragma("unroll") for (int q_ = 0; q_ < NQ; ++q_)                      \
            p[q_] = rs_ ? 0.0f : p[q_];                                        \
      }                                                                        \
      float sa_[NQ], ca_[NQ];                                                  \
      _Pragma("unroll") for (int q_ = 0; q_ < NQ; ++q_) {                      \
        const float rev_ = fmaf(p[q_], INV2PI, BUF[j_][q_]);                   \
        sa_[q_] = __builtin_amdgcn_sinf(rev_);                                 \
        ca_[q_] = __builtin_amdgcn_cosf(rev_);                                 \
      }                                                                        \
      const float t01_ = ca_[0] * ca_[1];                                      \
      const float t23_ = ca_[2] * ca_[3];                                      \
      const float t45_ = ca_[4] * ca_[5];                                      \
      const float P2_ = t01_ * ca_[2];                                         \
      const float P3_ = t01_ * t23_;                                           \
      const float P4_ = P3_ * ca_[4];                                          \
      const float P5_ = P3_ * t45_;                                            \
      p[0] = cth[0] * ca_[0] - sth[0] * (sa_[0] * sa_[1]);                     \
      p[1] = cth[1] * t01_ - sth[1] * (sa_[1] * sa_[2]);                       \
      p[2] = cth[2] * P2_ - sth[2] * (sa_[2] * sa_[3]);                        \
      p[3] = cth[3] * P3_ - sth[3] * (sa_[3] * sa_[4]);                        \
      p[4] = cth[4] * P4_ - sth[4] * (sa_[4] * sa_[5]);                        \
      p[5] = cth[5] * P5_ - sth[5] * sa_[5];                                   \
      if (i_ >= W) { /* uniform: i_ is compile-time */                         \
        if (((i_ - W) & 1) == 0) { /* even output step: buffer the row */      \
          _Pragma("unroll") for (int q_ = 0; q_ < NQ; ++q_) sv[q_] = p[q_];    \
        } else { /* odd: emit rows i_-1,i_ as 3x float4 (48 B, 16B-aligned) */ \
          float* bp_ = ob + (size_t)(tbase + i_ - 1) * NQ;                     \
          *(float4*)(bp_ + 0) = make_float4(sv[0], sv[1], sv[2], sv[3]);       \
          *(float4*)(bp_ + 4) = make_float4(sv[4], sv[5], p[0], p[1]);         \
          *(float4*)(bp_ + 8) = make_float4(p[2], p[3], p[4], p[5]);           \
        }                                                                      \
      }                                                                        \
    }                                                                          \
  } while (0)

  LOADG(0, bufA);
#pragma unroll
  for (int gi = 0; gi < NG; gi += 2) {  // fully unrolled; gi compile-time
    if (gi + 1 < NG) LOADG(gi + 1, bufB);
    __builtin_amdgcn_sched_barrier(0);  // loads stay batched ahead of compute
    STEPS(gi, bufA);
    if (gi + 2 < NG) LOADG(gi + 2, bufA);
    __builtin_amdgcn_sched_barrier(0);
    STEPS(gi + 1, bufB);
  }
#undef LOADG
#undef STEPS
}

extern "C" void kernel_launch(void* const* d_in, const int* in_sizes, int n_in,
                              void* d_out, int out_size, void* d_ws, size_t ws_size,
                              hipStream_t stream) {
  const float* x = (const float*)d_in[0];
  const float* w = (const float*)d_in[1];
  float* out = (float*)d_out;
  const int chains = in_sizes[0] / (T * 16);        // 2048
  const int blocks = chains * WPC / 64;             // 512 one-wave blocks
  qru_kernel<<<blocks, 64, 0, stream>>>(x, w, out);
}